// Round 14
// baseline (290.570 us; speedup 1.0000x reference)
//
#include <hip/hip_runtime.h>
#include <hip/hip_bf16.h>

// GCN graph classifier: 3x (GCNConv -> BN -> ReLU) -> sum-pool -> MLP head.
//   Hs[i] = (relu_bn(x[i])@W.T + b) * rdeg[i]   (MFMA bf16 gemm, packed-W frags, BN fused)
//   V[d]  = rdeg[d]*(Hs[d] + sum_in Hs[s])      (CSR gather; CHANNEL-HALF per block parity
//                                                -> per-XCD working set halves; 8 lanes/node
//                                                uint2, depth-8 branch-free MLP; BN stats
//                                                fused via shuffle-reduce -> striped partials)
// CSR via 2-level bucket sort (256-node buckets, line-dense writes, LDS atomics only).
// k_front = bucket histogram + W-pack + partial-zero in one launch.

#define NN 100000
#define NE 1600000
#define INF_ 128
#define HF 64
#define OUTF 10
#define NG 128
#define NBUCK 391     // ceil(NN/256)
#define NBLKP 512     // partition blocks; NE % NBLKP == 0 -> 3125 edges/block
#define CPB (NE / NBLKP)
#define NPART 32      // stats partial slots
#define PARTF (3 * NPART * 128 + NG * HF)   // floats zeroed by k_front = 20480

typedef short bf16x8 __attribute__((ext_vector_type(8)));
typedef float f32x4 __attribute__((ext_vector_type(4)));

static __device__ __forceinline__ unsigned short f2bf(float x) {
    unsigned int b = __float_as_uint(x);
    b += 0x7FFFu + ((b >> 16) & 1u);   // RNE
    return (unsigned short)(b >> 16);
}
static __device__ __forceinline__ float bf2f(unsigned short u) {
    return __uint_as_float(((unsigned int)u) << 16);
}
static __device__ __forceinline__ float bflo(unsigned int u) {
    return __uint_as_float(u << 16);
}
static __device__ __forceinline__ float bfhi(unsigned int u) {
    return __uint_as_float(u & 0xffff0000u);
}

// ---- front kernel: blocks [0,512) bucket-histogram; [512,520) W-pack; [520,600) zero part.
__global__ __launch_bounds__(256) void k_front(const int* __restrict__ dst,
                                               int* __restrict__ gcount,
                                               const float* __restrict__ W1f,
                                               const float* __restrict__ W2f,
                                               const float* __restrict__ W3f,
                                               unsigned short* __restrict__ wp0,
                                               unsigned short* __restrict__ wp1,
                                               unsigned short* __restrict__ wp2,
                                               float* __restrict__ part) {
    int t = threadIdx.x, b = blockIdx.x;
    if (b < NBLKP) {
        __shared__ int cnt[NBUCK];
        for (int i = t; i < NBUCK; i += 256) cnt[i] = 0;
        __syncthreads();
        int beg = b * CPB, end = beg + CPB;
        for (int i = beg + t; i < end; i += 256) atomicAdd(&cnt[dst[i] >> 8], 1);
        __syncthreads();
        for (int i = t; i < NBUCK; i += 256) gcount[i * NBLKP + b] = cnt[i];
    } else if (b < NBLKP + 8) {
        int bb = b - NBLKP;
        const float* W;
        unsigned short* P;
        int K, base;
        if (bb < 4)      { W = W1f; P = wp0; K = INF_; base = bb; }
        else if (bb < 6) { W = W2f; P = wp1; K = HF;   base = bb - 4; }
        else             { W = W3f; P = wp2; K = HF;   base = bb - 6; }
        int q = base * 256 + t;
        int nchunk = (K >> 5) << 8;
        if (q >= nchunk) return;
        int kb = q >> 8;
        int gq = (q >> 6) & 3;
        int ch = q & 63;
        const float* wr = W + (size_t)ch * K;
        unsigned int u[4];
#pragma unroll
        for (int i = 0; i < 4; ++i) {
            int e0 = 2 * i, e1 = 2 * i + 1;
            int k0 = kb * 32 + 4 * gq + (e0 & 3) + 16 * (e0 >> 2);
            int k1 = kb * 32 + 4 * gq + (e1 & 3) + 16 * (e1 >> 2);
            u[i] = (unsigned int)f2bf(wr[k0]) | ((unsigned int)f2bf(wr[k1]) << 16);
        }
        *(uint4*)(P + (size_t)q * 8) = make_uint4(u[0], u[1], u[2], u[3]);
    } else {
        int i = (b - NBLKP - 8) * 256 + t;
        if (i < PARTF) part[i] = 0.f;
    }
}

__global__ void k_scan1(const int* __restrict__ cnt, int* __restrict__ ro,
                        int* __restrict__ bsum, int n) {
    __shared__ int ts[256];
    int base = blockIdx.x * 1024 + threadIdx.x * 4;
    int v[4], s = 0;
#pragma unroll
    for (int k = 0; k < 4; ++k) {
        int idx = base + k;
        v[k] = (idx < n) ? cnt[idx] : 0;
        s += v[k];
    }
    ts[threadIdx.x] = s;
    __syncthreads();
    for (int off = 1; off < 256; off <<= 1) {
        int t = (threadIdx.x >= off) ? ts[threadIdx.x - off] : 0;
        __syncthreads();
        ts[threadIdx.x] += t;
        __syncthreads();
    }
    int ex = ts[threadIdx.x] - s;
    if (threadIdx.x == 255) bsum[blockIdx.x] = ts[255];
#pragma unroll
    for (int k = 0; k < 4; ++k) {
        int idx = base + k;
        if (idx < n) ro[idx] = ex;
        ex += v[k];
    }
}

// Single block, 256 threads: exclusive scan of nb (<=256) block sums in place.
__global__ void k_scan2(int* __restrict__ bsum, int nb) {
    __shared__ int ts[256];
    int i = threadIdx.x;
    int v = (i < nb) ? bsum[i] : 0;
    ts[i] = v;
    __syncthreads();
    for (int off = 1; off < 256; off <<= 1) {
        int t = (i >= off) ? ts[i - off] : 0;
        __syncthreads();
        ts[i] += t;
        __syncthreads();
    }
    if (i < nb) bsum[i] = ts[i] - v;
}

// Partition edges into bucket-major, block-private runs (bsum folded in).
__global__ __launch_bounds__(256) void kB_part(const int* __restrict__ src,
                                               const int* __restrict__ dst,
                                               const int* __restrict__ goff,
                                               const int* __restrict__ bsum,
                                               int* __restrict__ tmp) {
    __shared__ int cur[NBUCK];
    int t = threadIdx.x, blk = blockIdx.x;
    for (int i = t; i < NBUCK; i += 256) {
        int idx = i * NBLKP + blk;
        cur[i] = goff[idx] + bsum[idx >> 10];
    }
    __syncthreads();
    int beg = blk * CPB, end = beg + CPB;
    for (int i = beg + t; i < end; i += 256) {
        int d = dst[i];
        int pos = atomicAdd(&cur[d >> 8], 1);
        tmp[pos] = ((d & 255) << 17) | src[i];
    }
}

// One block per 256-node bucket: per-node hist+scan -> ro, rdeg, node-sorted ss.
__global__ __launch_bounds__(256) void kC_build(const int* __restrict__ goff,
                                                const int* __restrict__ bsum,
                                                int* __restrict__ tmp,
                                                int* __restrict__ ss,
                                                int* __restrict__ ro,
                                                float* __restrict__ rdeg, int E) {
    __shared__ int cnt[256];
    __shared__ int ts[256];
    __shared__ int cur[256];
    int t = threadIdx.x, b = blockIdx.x;
    int i0 = b * NBLKP;
    int beg = goff[i0] + bsum[i0 >> 10];
    int end = E;
    if (b + 1 < NBUCK) {
        int i1 = (b + 1) * NBLKP;
        end = goff[i1] + bsum[i1 >> 10];
    }
    cnt[t] = 0;
    __syncthreads();
    for (int i = beg + t; i < end; i += 256) atomicAdd(&cnt[tmp[i] >> 17], 1);
    __syncthreads();
    int s = cnt[t];
    ts[t] = s;
    __syncthreads();
    for (int off = 1; off < 256; off <<= 1) {
        int v = (t >= off) ? ts[t - off] : 0;
        __syncthreads();
        ts[t] += v;
        __syncthreads();
    }
    int p = beg + ts[t] - s;
    cur[t] = p;
    int node = (b << 8) + t;
    if (node < NN) {
        ro[node] = p;
        rdeg[node] = rsqrtf((float)s + 1.f);
    } else if (node == NN) {
        ro[NN] = p;
    }
    __syncthreads();
    for (int i = beg + t; i < end; i += 256) {
        int pk = tmp[i];
        int pos = atomicAdd(&cur[pk >> 17], 1);
        ss[pos] = pk & 0x1FFFF;
    }
}

// ---- MFMA GEMM: 64-row tile, 256 threads (4 waves), wave w -> rows [16w,16w+16).
// BN params derived from NPART-slot partial sums (SP) produced by k_agg.
template<int K, bool BN>
__global__ __launch_bounds__(256) void k_gemm_mfma(const float* __restrict__ Xf,
                                                   const unsigned short* __restrict__ Xh,
                                                   const unsigned short* __restrict__ Wp,
                                                   const float* __restrict__ bias,
                                                   const float* __restrict__ rdeg,
                                                   const float* __restrict__ SP,
                                                   const float* __restrict__ g,
                                                   const float* __restrict__ be,
                                                   unsigned short* __restrict__ Hs, int n) {
    constexpr int KB = K / 32;       // k-steps
    constexpr int RB = K * 2;        // LDS row bytes (bf16)
    __shared__ __align__(16) char raw[64 * 68 * 4];  // stage bf16[64][K] / out f32[64][68]
    __shared__ float sa_l[64], sb_l[64];
    const int t = threadIdx.x;
    const int w = t >> 6;
    const int c = t & 15;            // lane&15
    const int gq = (t >> 4) & 3;     // lane>>4
    const int r0 = blockIdx.x * 64;

    if (BN && t < 64) {
        float s = 0.f, q = 0.f;
#pragma unroll
        for (int p = 0; p < NPART; ++p) {
            s += SP[p * 128 + t];
            q += SP[p * 128 + 64 + t];
        }
        float n_ = (float)NN;
        float mu = s / n_;
        float var = q / n_ - mu * mu;
        float a = g[t] * rsqrtf(var + 1e-5f);
        sa_l[t] = a;
        sb_l[t] = be[t] - mu * a;
    }
    __syncthreads();  // sa_l ready

    // Stage X tile: thread t handles row r=t>>2, channel chunk q=t&3.
    {
        int r = t >> 2, q = t & 3;
        int row = r0 + r;
        int x_swz = (r & 7) << 4;
        if (BN) {                     // K==64: 16 ch per thread from bf16 V
            int ch0 = q * 16;
            uint4 u0 = make_uint4(0, 0, 0, 0), u1 = make_uint4(0, 0, 0, 0);
            if (row < n) {
                const uint4* p = (const uint4*)(Xh + (size_t)row * 64 + ch0);
                u0 = p[0];
                u1 = p[1];
            }
            unsigned int uin[8] = {u0.x, u0.y, u0.z, u0.w, u1.x, u1.y, u1.z, u1.w};
            unsigned int uo[8];
#pragma unroll
            for (int j = 0; j < 8; ++j) {
                int chl = ch0 + 2 * j, chh = chl + 1;
                float v0 = fmaxf(fmaf(sa_l[chl], bflo(uin[j]), sb_l[chl]), 0.f);
                float v1 = fmaxf(fmaf(sa_l[chh], bfhi(uin[j]), sb_l[chh]), 0.f);
                uo[j] = (unsigned int)f2bf(v0) | ((unsigned int)f2bf(v1) << 16);
            }
            int b0 = r * RB + q * 32;
            *(uint4*)(raw + ((b0) ^ x_swz)) = make_uint4(uo[0], uo[1], uo[2], uo[3]);
            *(uint4*)(raw + ((b0 + 16) ^ x_swz)) = make_uint4(uo[4], uo[5], uo[6], uo[7]);
        } else {                      // K==128: 32 ch per thread from f32 x
            int ch0 = q * 32;
#pragma unroll
            for (int j2 = 0; j2 < 4; ++j2) {
                float4 a = make_float4(0.f, 0.f, 0.f, 0.f), b = make_float4(0.f, 0.f, 0.f, 0.f);
                if (row < n) {
                    const float4* p = (const float4*)(Xf + (size_t)row * K + ch0 + j2 * 8);
                    a = p[0];
                    b = p[1];
                }
                unsigned int q0 = (unsigned int)f2bf(a.x) | ((unsigned int)f2bf(a.y) << 16);
                unsigned int q1 = (unsigned int)f2bf(a.z) | ((unsigned int)f2bf(a.w) << 16);
                unsigned int q2 = (unsigned int)f2bf(b.x) | ((unsigned int)f2bf(b.y) << 16);
                unsigned int q3 = (unsigned int)f2bf(b.z) | ((unsigned int)f2bf(b.w) << 16);
                int b0 = r * RB + ch0 * 2 + j2 * 16;
                *(uint4*)(raw + (b0 ^ x_swz)) = make_uint4(q0, q1, q2, q3);
            }
        }
    }
    __syncthreads();

    // A fragments from LDS + MFMA with packed-W loads.
    bf16x8 af[KB];
    {
        int r = 16 * w + c;
        int rb = r * RB;
        int swz = (r & 7) << 4;
#pragma unroll
        for (int kb = 0; kb < KB; ++kb) {
            int off = rb + kb * 64 + gq * 8;
            uint2 u0 = *(const uint2*)(raw + (off ^ swz));
            uint2 u1 = *(const uint2*)(raw + ((off + 32) ^ swz));
            union { uint4 u; bf16x8 v; } cv;
            cv.u = make_uint4(u0.x, u0.y, u1.x, u1.y);
            af[kb] = cv.v;
        }
    }
    const uint4* wq = (const uint4*)Wp;
    f32x4 acc[4];
#pragma unroll
    for (int nn_ = 0; nn_ < 4; ++nn_) {
        acc[nn_] = (f32x4){0.f, 0.f, 0.f, 0.f};
#pragma unroll
        for (int kb = 0; kb < KB; ++kb) {
            union { uint4 u; bf16x8 v; } cw;
            cw.u = wq[(kb * 4 + gq) * 64 + nn_ * 16 + c];
            acc[nn_] = __builtin_amdgcn_mfma_f32_16x16x32_bf16(af[kb], cw.v, acc[nn_], 0, 0, 0);
        }
    }

    // Epilogue: (acc + bias) * rdeg -> LDS f32 [64][68] -> coalesced bf16 store.
    __syncthreads();
    float* outb = (float*)raw;
    float rv[4];
#pragma unroll
    for (int i = 0; i < 4; ++i) {
        int rg = r0 + 16 * w + 4 * gq + i;
        rv[i] = (rg < n) ? rdeg[rg] : 0.f;
    }
#pragma unroll
    for (int nn_ = 0; nn_ < 4; ++nn_) {
        int col = 16 * nn_ + c;
        float bz = bias[col];
#pragma unroll
        for (int i = 0; i < 4; ++i)
            outb[(16 * w + 4 * gq + i) * 68 + col] = (acc[nn_][i] + bz) * rv[i];
    }
    __syncthreads();
    {
        int r = t >> 2, q = t & 3;
        int row = r0 + r;
        if (row < n) {
            const float* src = outb + r * 68 + q * 16;
            unsigned int u[8];
#pragma unroll
            for (int j = 0; j < 8; ++j)
                u[j] = (unsigned int)f2bf(src[2 * j]) | ((unsigned int)f2bf(src[2 * j + 1]) << 16);
            uint4* p = (uint4*)(Hs + (size_t)row * HF + q * 16);
            p[0] = make_uint4(u[0], u[1], u[2], u[3]);
            p[1] = make_uint4(u[4], u[5], u[6], u[7]);
        }
    }
}

// Aggregation v4: channel-half per block parity (blockIdx&1 -> XCD-parity partition,
// halves each XCD's L2 working set). 8 lanes/node x uint2 (4 ch), 8 nodes/wave,
// depth-8 branch-free MLP batches. Stats: slot shfl_xor reduce -> per-wave LDS ->
// 64 striped atomics/block (channel-half only).
__global__ __launch_bounds__(256) void k_agg(const int* __restrict__ ro,
                                             const int* __restrict__ ss,
                                             const unsigned short* __restrict__ Hs,
                                             const float* __restrict__ rdeg,
                                             unsigned short* __restrict__ V16,
                                             float* __restrict__ partial, int n) {
    __shared__ float red[4][64];
    int t = threadIdx.x;
    int h = blockIdx.x & 1;            // channel half
    int blk = blockIdx.x >> 1;
    int wv = t >> 6;
    int lane = t & 63;
    int sub = lane >> 3;               // node slot (8 per wave)
    int lq = lane & 7;                 // lane within slot
    int co = h * 32 + lq * 4;          // channel offset within row
    int node = blk * 32 + wv * 8 + sub;
    bool vn = node < n;
    int safe = vn ? node : 0;
    int beg = 0, d = 0;
    if (vn) {
        beg = ro[node];
        d = ro[node + 1] - beg;
    }
    float4 acc = make_float4(0.f, 0.f, 0.f, 0.f);
    if (vn) {
        uint2 u = *(const uint2*)(Hs + ((size_t)node << 6) + co);
        acc.x = bflo(u.x); acc.y = bfhi(u.x); acc.z = bflo(u.y); acc.w = bfhi(u.y);
    }
    int dm = d;
    dm = max(dm, __shfl_xor(dm, 8));
    dm = max(dm, __shfl_xor(dm, 16));
    dm = max(dm, __shfl_xor(dm, 32));
    for (int it = 0; it < dm; it += 8) {
        int myidx = (it + lq < d) ? ss[beg + it + lq] : -1;
        int sidx[8];
        float msk[8];
#pragma unroll
        for (int k = 0; k < 8; ++k) {
            int s = __shfl(myidx, (sub << 3) + k);
            sidx[k] = (s >= 0) ? s : safe;
            msk[k] = (s >= 0) ? 1.f : 0.f;
        }
        uint2 u[8];
#pragma unroll
        for (int k = 0; k < 8; ++k)
            u[k] = *(const uint2*)(Hs + ((size_t)sidx[k] << 6) + co);
#pragma unroll
        for (int k = 0; k < 8; ++k) {
            acc.x = fmaf(msk[k], bflo(u[k].x), acc.x);
            acc.y = fmaf(msk[k], bfhi(u[k].x), acc.y);
            acc.z = fmaf(msk[k], bflo(u[k].y), acc.z);
            acc.w = fmaf(msk[k], bfhi(u[k].y), acc.w);
        }
    }
    float rv = vn ? rdeg[node] : 0.f;
    float v0 = acc.x * rv, v1 = acc.y * rv, v2 = acc.z * rv, v3 = acc.w * rv;
    if (vn) {
        unsigned int p0 = (unsigned int)f2bf(v0) | ((unsigned int)f2bf(v1) << 16);
        unsigned int p1 = (unsigned int)f2bf(v2) | ((unsigned int)f2bf(v3) << 16);
        *(uint2*)(V16 + ((size_t)node << 6) + co) = make_uint2(p0, p1);
    }
    // fused BN stats for this channel half: reduce across the 8 node slots
    float s0 = v0, s1 = v1, s2 = v2, s3 = v3;
    float q0 = v0 * v0, q1 = v1 * v1, q2 = v2 * v2, q3 = v3 * v3;
#pragma unroll
    for (int m = 8; m <= 32; m <<= 1) {
        s0 += __shfl_xor(s0, m); s1 += __shfl_xor(s1, m);
        s2 += __shfl_xor(s2, m); s3 += __shfl_xor(s3, m);
        q0 += __shfl_xor(q0, m); q1 += __shfl_xor(q1, m);
        q2 += __shfl_xor(q2, m); q3 += __shfl_xor(q3, m);
    }
    if (sub == 0) {
        red[wv][lq * 4 + 0] = s0; red[wv][lq * 4 + 1] = s1;
        red[wv][lq * 4 + 2] = s2; red[wv][lq * 4 + 3] = s3;
        red[wv][32 + lq * 4 + 0] = q0; red[wv][32 + lq * 4 + 1] = q1;
        red[wv][32 + lq * 4 + 2] = q2; red[wv][32 + lq * 4 + 3] = q3;
    }
    __syncthreads();
    if (t < 64) {
        float r = red[0][t] + red[1][t] + red[2][t] + red[3][t];
        int slot = blockIdx.x & (NPART - 1);
        int dest;
        if (t < 32) dest = slot * 128 + h * 32 + t;              // sums
        else        dest = slot * 128 + 64 + h * 32 + (t - 32);  // sumsqs
        atomicAdd(&partial[dest], r);
    }
}

// Pool: wave per 64 consecutive rows, run-flush atomics at graph boundaries.
// BN params from NPART-slot partials.
__global__ __launch_bounds__(256) void k_pool2(const unsigned short* __restrict__ V16,
                                               const float* __restrict__ SP,
                                               const float* __restrict__ g,
                                               const float* __restrict__ be,
                                               const int* __restrict__ batch,
                                               float* __restrict__ pool, int n) {
    __shared__ float sa_l[64], sb_l[64];
    int t = threadIdx.x;
    if (t < 64) {
        float s = 0.f, q = 0.f;
#pragma unroll
        for (int p = 0; p < NPART; ++p) {
            s += SP[p * 128 + t];
            q += SP[p * 128 + 64 + t];
        }
        float n_ = (float)NN;
        float mu = s / n_;
        float var = q / n_ - mu * mu;
        float a = g[t] * rsqrtf(var + 1e-5f);
        sa_l[t] = a;
        sb_l[t] = be[t] - mu * a;
    }
    __syncthreads();
    int wid = blockIdx.x * 4 + (t >> 6);
    int r0 = wid * 64;
    if (r0 >= n) return;
    int lane = t & 63;
    float sa = sa_l[lane], sb = sb_l[lane];
    int rend = min(r0 + 64, n);
    int cur = batch[r0];
    float s = 0.f;
    for (int r = r0; r < rend; ++r) {
        int b = batch[r];
        if (b != cur) {
            atomicAdd(&pool[(size_t)cur * HF + lane], s);
            s = 0.f;
            cur = b;
        }
        float v = bf2f(V16[(size_t)r * HF + lane]);
        s += fmaxf(fmaf(sa, v, sb), 0.f);
    }
    atomicAdd(&pool[(size_t)cur * HF + lane], s);
}

__global__ void k_cls(const float* __restrict__ pool, const float* __restrict__ Wc1,
                      const float* __restrict__ bc1, const float* __restrict__ Wc2,
                      const float* __restrict__ bc2, float* __restrict__ out) {
    __shared__ float pl[HF], hr[HF];
    int g = blockIdx.x, c = threadIdx.x;
    pl[c] = pool[g * HF + c];
    __syncthreads();
    float h = bc1[c];
#pragma unroll
    for (int k = 0; k < HF; ++k) h = fmaf(pl[k], Wc1[c * HF + k], h);
    hr[c] = fmaxf(h, 0.f);
    __syncthreads();
    if (c < OUTF) {
        float o = bc2[c];
#pragma unroll
        for (int k = 0; k < HF; ++k) o = fmaf(hr[k], Wc2[c * HF + k], o);
        out[g * OUTF + c] = o;
    }
}

extern "C" void kernel_launch(void* const* d_in, const int* in_sizes, int n_in,
                              void* d_out, int out_size, void* d_ws, size_t ws_size,
                              hipStream_t stream) {
    const float* x = (const float*)d_in[0];
    const int* edge = (const int*)d_in[1];
    const int* batch = (const int*)d_in[2];
    const float* W1 = (const float*)d_in[3];
    const float* b1 = (const float*)d_in[4];
    const float* g1 = (const float*)d_in[5];
    const float* be1 = (const float*)d_in[6];
    const float* W2 = (const float*)d_in[7];
    const float* b2 = (const float*)d_in[8];
    const float* g2 = (const float*)d_in[9];
    const float* be2 = (const float*)d_in[10];
    const float* W3 = (const float*)d_in[11];
    const float* b3 = (const float*)d_in[12];
    const float* g3 = (const float*)d_in[13];
    const float* be3 = (const float*)d_in[14];
    const float* Wc1 = (const float*)d_in[15];
    const float* bc1 = (const float*)d_in[16];
    const float* Wc2 = (const float*)d_in[17];
    const float* bc2 = (const float*)d_in[18];
    float* out = (float*)d_out;

    const int* src = edge;
    const int* dst = edge + NE;

    const size_t N64 = (size_t)NN * HF;
    const int NGC = NBUCK * NBLKP;                       // 200192
    unsigned short* V16 = (unsigned short*)d_ws;         // N*64 bf16
    unsigned short* Hs = V16 + N64;                      // N*64 bf16
    float* rdeg = (float*)(Hs + N64);                    // N
    float* part = rdeg + NN;                             // 3 * NPART*128 (per-layer partials)
    float* pool = part + 3 * NPART * 128;                // NG*64 (contiguous w/ part)
    int* gcount = (int*)(pool + (size_t)NG * HF);        // NGC
    int* goff = gcount + NGC;                            // NGC
    int* bsum = goff + NGC;                              // 256
    int* ro = bsum + 256;                                // N+1
    int* tmp = ro + NN + 1;                              // E
    int* ss = tmp + NE;                                  // E
    unsigned short* wp0 = (unsigned short*)(ss + NE);    // 8192 (W1 pack)
    unsigned short* wp1 = wp0 + 8192;                    // 4096 (W2 pack)
    unsigned short* wp2 = wp1 + 4096;                    // 4096 (W3 pack)

    // ---- front: bucket histogram + W pack + partial zero (one launch) ----
    k_front<<<NBLKP + 8 + (PARTF + 255) / 256, 256, 0, stream>>>(
        dst, gcount, W1, W2, W3, wp0, wp1, wp2, part);

    // ---- CSR build ----
    const int nblk = (NGC + 1023) / 1024;                // 196
    k_scan1<<<nblk, 256, 0, stream>>>(gcount, goff, bsum, NGC);
    k_scan2<<<1, 256, 0, stream>>>(bsum, nblk);
    kB_part<<<NBLKP, 256, 0, stream>>>(src, dst, goff, bsum, tmp);
    kC_build<<<NBUCK, 256, 0, stream>>>(goff, bsum, tmp, ss, ro, rdeg, NE);

    const unsigned short* gWp[3] = {wp0, wp1, wp2};
    const float* gb[3] = {b1, b2, b3};
    const float* gg[3] = {g1, g2, g3};
    const float* gbe[3] = {be1, be2, be3};

    const int tileblk = (NN + 63) / 64;
    const int aggblk = 2 * ((NN + 31) / 32);  // 2 channel-halves x 32 nodes/block
    const int poolblk = ((NN + 63) / 64 + 3) / 4;

    for (int l = 0; l < 3; ++l) {
        if (l == 0)
            k_gemm_mfma<INF_, false><<<tileblk, 256, 0, stream>>>(x, (const unsigned short*)0,
                                                                  gWp[0], gb[0], rdeg, part,
                                                                  gg[0], gbe[0], Hs, NN);
        else
            k_gemm_mfma<HF, true><<<tileblk, 256, 0, stream>>>((const float*)0, V16,
                                                               gWp[l], gb[l], rdeg,
                                                               part + (l - 1) * NPART * 128,
                                                               gg[l - 1], gbe[l - 1], Hs, NN);
        k_agg<<<aggblk, 256, 0, stream>>>(ro, ss, Hs, rdeg, V16,
                                          part + l * NPART * 128, NN);
        if (l == 2)
            k_pool2<<<poolblk, 256, 0, stream>>>(V16, part + 2 * NPART * 128,
                                                 gg[2], gbe[2], batch, pool, NN);
    }

    k_cls<<<NG, HF, 0, stream>>>(pool, Wc1, bc1, Wc2, bc2, out);
}

// Round 15
// 225.391 us; speedup vs baseline: 1.2892x; 1.2892x over previous
//
#include <hip/hip_runtime.h>
#include <hip/hip_bf16.h>

// GCN graph classifier: 3x (GCNConv -> BN -> ReLU) -> sum-pool -> MLP head.
//   Hs[i] = (relu_bn(x[i])@W.T + b) * rdeg[i]   (MFMA bf16 gemm, packed-W frags, BN fused)
//   V[d]  = rdeg[d]*(Hs[d] + sum_in Hs[s])      (CSR gather; quarter-wave/node, depth-16
//                                                branch-free MLP; BN stats fused via
//                                                shuffle-reduce -> striped partials)
// CSR via 2-level bucket sort (256-node buckets, line-dense writes, LDS atomics only).
// k_front = bucket histogram + W-pack + partial-zero in one launch; scan3 folded into
// kB/kC via inline bsum add. Pool = run-flush segmented sum over sorted batch.
// NOTE (R14 lesson): k_agg must consume FULL 128B rows per gather — channel-splitting
// doubles TCC line fetches (128B line granularity) and regresses.

#define NN 100000
#define NE 1600000
#define INF_ 128
#define HF 64
#define OUTF 10
#define NG 128
#define NBUCK 391     // ceil(NN/256)
#define NBLKP 512     // partition blocks; NE % NBLKP == 0 -> 3125 edges/block
#define CPB (NE / NBLKP)
#define NPART 32      // stats partial slots
#define PARTF (3 * NPART * 128 + NG * HF)   // floats zeroed by k_front = 20480

typedef short bf16x8 __attribute__((ext_vector_type(8)));
typedef float f32x4 __attribute__((ext_vector_type(4)));

static __device__ __forceinline__ unsigned short f2bf(float x) {
    unsigned int b = __float_as_uint(x);
    b += 0x7FFFu + ((b >> 16) & 1u);   // RNE
    return (unsigned short)(b >> 16);
}
static __device__ __forceinline__ float bf2f(unsigned short u) {
    return __uint_as_float(((unsigned int)u) << 16);
}
static __device__ __forceinline__ float bflo(unsigned int u) {
    return __uint_as_float(u << 16);
}
static __device__ __forceinline__ float bfhi(unsigned int u) {
    return __uint_as_float(u & 0xffff0000u);
}

// ---- front kernel: blocks [0,512) bucket-histogram; [512,520) W-pack; [520,600) zero part.
__global__ __launch_bounds__(256) void k_front(const int* __restrict__ dst,
                                               int* __restrict__ gcount,
                                               const float* __restrict__ W1f,
                                               const float* __restrict__ W2f,
                                               const float* __restrict__ W3f,
                                               unsigned short* __restrict__ wp0,
                                               unsigned short* __restrict__ wp1,
                                               unsigned short* __restrict__ wp2,
                                               float* __restrict__ part) {
    int t = threadIdx.x, b = blockIdx.x;
    if (b < NBLKP) {
        __shared__ int cnt[NBUCK];
        for (int i = t; i < NBUCK; i += 256) cnt[i] = 0;
        __syncthreads();
        int beg = b * CPB, end = beg + CPB;
        for (int i = beg + t; i < end; i += 256) atomicAdd(&cnt[dst[i] >> 8], 1);
        __syncthreads();
        for (int i = t; i < NBUCK; i += 256) gcount[i * NBLKP + b] = cnt[i];
    } else if (b < NBLKP + 8) {
        int bb = b - NBLKP;
        const float* W;
        unsigned short* P;
        int K, base;
        if (bb < 4)      { W = W1f; P = wp0; K = INF_; base = bb; }
        else if (bb < 6) { W = W2f; P = wp1; K = HF;   base = bb - 4; }
        else             { W = W3f; P = wp2; K = HF;   base = bb - 6; }
        int q = base * 256 + t;
        int nchunk = (K >> 5) << 8;
        if (q >= nchunk) return;
        int kb = q >> 8;
        int gq = (q >> 6) & 3;
        int ch = q & 63;
        const float* wr = W + (size_t)ch * K;
        unsigned int u[4];
#pragma unroll
        for (int i = 0; i < 4; ++i) {
            int e0 = 2 * i, e1 = 2 * i + 1;
            int k0 = kb * 32 + 4 * gq + (e0 & 3) + 16 * (e0 >> 2);
            int k1 = kb * 32 + 4 * gq + (e1 & 3) + 16 * (e1 >> 2);
            u[i] = (unsigned int)f2bf(wr[k0]) | ((unsigned int)f2bf(wr[k1]) << 16);
        }
        *(uint4*)(P + (size_t)q * 8) = make_uint4(u[0], u[1], u[2], u[3]);
    } else {
        int i = (b - NBLKP - 8) * 256 + t;
        if (i < PARTF) part[i] = 0.f;
    }
}

__global__ void k_scan1(const int* __restrict__ cnt, int* __restrict__ ro,
                        int* __restrict__ bsum, int n) {
    __shared__ int ts[256];
    int base = blockIdx.x * 1024 + threadIdx.x * 4;
    int v[4], s = 0;
#pragma unroll
    for (int k = 0; k < 4; ++k) {
        int idx = base + k;
        v[k] = (idx < n) ? cnt[idx] : 0;
        s += v[k];
    }
    ts[threadIdx.x] = s;
    __syncthreads();
    for (int off = 1; off < 256; off <<= 1) {
        int t = (threadIdx.x >= off) ? ts[threadIdx.x - off] : 0;
        __syncthreads();
        ts[threadIdx.x] += t;
        __syncthreads();
    }
    int ex = ts[threadIdx.x] - s;
    if (threadIdx.x == 255) bsum[blockIdx.x] = ts[255];
#pragma unroll
    for (int k = 0; k < 4; ++k) {
        int idx = base + k;
        if (idx < n) ro[idx] = ex;
        ex += v[k];
    }
}

// Single block, 256 threads: exclusive scan of nb (<=256) block sums in place.
__global__ void k_scan2(int* __restrict__ bsum, int nb) {
    __shared__ int ts[256];
    int i = threadIdx.x;
    int v = (i < nb) ? bsum[i] : 0;
    ts[i] = v;
    __syncthreads();
    for (int off = 1; off < 256; off <<= 1) {
        int t = (i >= off) ? ts[i - off] : 0;
        __syncthreads();
        ts[i] += t;
        __syncthreads();
    }
    if (i < nb) bsum[i] = ts[i] - v;
}

// Partition edges into bucket-major, block-private runs (bsum folded in).
__global__ __launch_bounds__(256) void kB_part(const int* __restrict__ src,
                                               const int* __restrict__ dst,
                                               const int* __restrict__ goff,
                                               const int* __restrict__ bsum,
                                               int* __restrict__ tmp) {
    __shared__ int cur[NBUCK];
    int t = threadIdx.x, blk = blockIdx.x;
    for (int i = t; i < NBUCK; i += 256) {
        int idx = i * NBLKP + blk;
        cur[i] = goff[idx] + bsum[idx >> 10];
    }
    __syncthreads();
    int beg = blk * CPB, end = beg + CPB;
    for (int i = beg + t; i < end; i += 256) {
        int d = dst[i];
        int pos = atomicAdd(&cur[d >> 8], 1);
        tmp[pos] = ((d & 255) << 17) | src[i];
    }
}

// One block per 256-node bucket: per-node hist+scan -> ro, rdeg, node-sorted ss.
__global__ __launch_bounds__(256) void kC_build(const int* __restrict__ goff,
                                                const int* __restrict__ bsum,
                                                int* __restrict__ tmp,
                                                int* __restrict__ ss,
                                                int* __restrict__ ro,
                                                float* __restrict__ rdeg, int E) {
    __shared__ int cnt[256];
    __shared__ int ts[256];
    __shared__ int cur[256];
    int t = threadIdx.x, b = blockIdx.x;
    int i0 = b * NBLKP;
    int beg = goff[i0] + bsum[i0 >> 10];
    int end = E;
    if (b + 1 < NBUCK) {
        int i1 = (b + 1) * NBLKP;
        end = goff[i1] + bsum[i1 >> 10];
    }
    cnt[t] = 0;
    __syncthreads();
    for (int i = beg + t; i < end; i += 256) atomicAdd(&cnt[tmp[i] >> 17], 1);
    __syncthreads();
    int s = cnt[t];
    ts[t] = s;
    __syncthreads();
    for (int off = 1; off < 256; off <<= 1) {
        int v = (t >= off) ? ts[t - off] : 0;
        __syncthreads();
        ts[t] += v;
        __syncthreads();
    }
    int p = beg + ts[t] - s;
    cur[t] = p;
    int node = (b << 8) + t;
    if (node < NN) {
        ro[node] = p;
        rdeg[node] = rsqrtf((float)s + 1.f);
    } else if (node == NN) {
        ro[NN] = p;
    }
    __syncthreads();
    for (int i = beg + t; i < end; i += 256) {
        int pk = tmp[i];
        int pos = atomicAdd(&cur[pk >> 17], 1);
        ss[pos] = pk & 0x1FFFF;
    }
}

// ---- MFMA GEMM: 64-row tile, 256 threads (4 waves), wave w -> rows [16w,16w+16).
// BN params derived from NPART-slot partial sums (SP) produced by k_agg.
template<int K, bool BN>
__global__ __launch_bounds__(256) void k_gemm_mfma(const float* __restrict__ Xf,
                                                   const unsigned short* __restrict__ Xh,
                                                   const unsigned short* __restrict__ Wp,
                                                   const float* __restrict__ bias,
                                                   const float* __restrict__ rdeg,
                                                   const float* __restrict__ SP,
                                                   const float* __restrict__ g,
                                                   const float* __restrict__ be,
                                                   unsigned short* __restrict__ Hs, int n) {
    constexpr int KB = K / 32;       // k-steps
    constexpr int RB = K * 2;        // LDS row bytes (bf16)
    __shared__ __align__(16) char raw[64 * 68 * 4];  // stage bf16[64][K] / out f32[64][68]
    __shared__ float sa_l[64], sb_l[64];
    const int t = threadIdx.x;
    const int w = t >> 6;
    const int c = t & 15;            // lane&15
    const int gq = (t >> 4) & 3;     // lane>>4
    const int r0 = blockIdx.x * 64;

    if (BN && t < 64) {
        float s = 0.f, q = 0.f;
#pragma unroll
        for (int p = 0; p < NPART; ++p) {
            s += SP[p * 128 + t];
            q += SP[p * 128 + 64 + t];
        }
        float n_ = (float)NN;
        float mu = s / n_;
        float var = q / n_ - mu * mu;
        float a = g[t] * rsqrtf(var + 1e-5f);
        sa_l[t] = a;
        sb_l[t] = be[t] - mu * a;
    }
    __syncthreads();  // sa_l ready

    // Stage X tile: thread t handles row r=t>>2, channel chunk q=t&3.
    {
        int r = t >> 2, q = t & 3;
        int row = r0 + r;
        int x_swz = (r & 7) << 4;
        if (BN) {                     // K==64: 16 ch per thread from bf16 V
            int ch0 = q * 16;
            uint4 u0 = make_uint4(0, 0, 0, 0), u1 = make_uint4(0, 0, 0, 0);
            if (row < n) {
                const uint4* p = (const uint4*)(Xh + (size_t)row * 64 + ch0);
                u0 = p[0];
                u1 = p[1];
            }
            unsigned int uin[8] = {u0.x, u0.y, u0.z, u0.w, u1.x, u1.y, u1.z, u1.w};
            unsigned int uo[8];
#pragma unroll
            for (int j = 0; j < 8; ++j) {
                int chl = ch0 + 2 * j, chh = chl + 1;
                float v0 = fmaxf(fmaf(sa_l[chl], bflo(uin[j]), sb_l[chl]), 0.f);
                float v1 = fmaxf(fmaf(sa_l[chh], bfhi(uin[j]), sb_l[chh]), 0.f);
                uo[j] = (unsigned int)f2bf(v0) | ((unsigned int)f2bf(v1) << 16);
            }
            int b0 = r * RB + q * 32;
            *(uint4*)(raw + ((b0) ^ x_swz)) = make_uint4(uo[0], uo[1], uo[2], uo[3]);
            *(uint4*)(raw + ((b0 + 16) ^ x_swz)) = make_uint4(uo[4], uo[5], uo[6], uo[7]);
        } else {                      // K==128: 32 ch per thread from f32 x
            int ch0 = q * 32;
#pragma unroll
            for (int j2 = 0; j2 < 4; ++j2) {
                float4 a = make_float4(0.f, 0.f, 0.f, 0.f), b = make_float4(0.f, 0.f, 0.f, 0.f);
                if (row < n) {
                    const float4* p = (const float4*)(Xf + (size_t)row * K + ch0 + j2 * 8);
                    a = p[0];
                    b = p[1];
                }
                unsigned int q0 = (unsigned int)f2bf(a.x) | ((unsigned int)f2bf(a.y) << 16);
                unsigned int q1 = (unsigned int)f2bf(a.z) | ((unsigned int)f2bf(a.w) << 16);
                unsigned int q2 = (unsigned int)f2bf(b.x) | ((unsigned int)f2bf(b.y) << 16);
                unsigned int q3 = (unsigned int)f2bf(b.z) | ((unsigned int)f2bf(b.w) << 16);
                int b0 = r * RB + ch0 * 2 + j2 * 16;
                *(uint4*)(raw + (b0 ^ x_swz)) = make_uint4(q0, q1, q2, q3);
            }
        }
    }
    __syncthreads();

    // A fragments from LDS + MFMA with packed-W loads.
    bf16x8 af[KB];
    {
        int r = 16 * w + c;
        int rb = r * RB;
        int swz = (r & 7) << 4;
#pragma unroll
        for (int kb = 0; kb < KB; ++kb) {
            int off = rb + kb * 64 + gq * 8;
            uint2 u0 = *(const uint2*)(raw + (off ^ swz));
            uint2 u1 = *(const uint2*)(raw + ((off + 32) ^ swz));
            union { uint4 u; bf16x8 v; } cv;
            cv.u = make_uint4(u0.x, u0.y, u1.x, u1.y);
            af[kb] = cv.v;
        }
    }
    const uint4* wq = (const uint4*)Wp;
    f32x4 acc[4];
#pragma unroll
    for (int nn_ = 0; nn_ < 4; ++nn_) {
        acc[nn_] = (f32x4){0.f, 0.f, 0.f, 0.f};
#pragma unroll
        for (int kb = 0; kb < KB; ++kb) {
            union { uint4 u; bf16x8 v; } cw;
            cw.u = wq[(kb * 4 + gq) * 64 + nn_ * 16 + c];
            acc[nn_] = __builtin_amdgcn_mfma_f32_16x16x32_bf16(af[kb], cw.v, acc[nn_], 0, 0, 0);
        }
    }

    // Epilogue: (acc + bias) * rdeg -> LDS f32 [64][68] -> coalesced bf16 store.
    __syncthreads();
    float* outb = (float*)raw;
    float rv[4];
#pragma unroll
    for (int i = 0; i < 4; ++i) {
        int rg = r0 + 16 * w + 4 * gq + i;
        rv[i] = (rg < n) ? rdeg[rg] : 0.f;
    }
#pragma unroll
    for (int nn_ = 0; nn_ < 4; ++nn_) {
        int col = 16 * nn_ + c;
        float bz = bias[col];
#pragma unroll
        for (int i = 0; i < 4; ++i)
            outb[(16 * w + 4 * gq + i) * 68 + col] = (acc[nn_][i] + bz) * rv[i];
    }
    __syncthreads();
    {
        int r = t >> 2, q = t & 3;
        int row = r0 + r;
        if (row < n) {
            const float* src = outb + r * 68 + q * 16;
            unsigned int u[8];
#pragma unroll
            for (int j = 0; j < 8; ++j)
                u[j] = (unsigned int)f2bf(src[2 * j]) | ((unsigned int)f2bf(src[2 * j + 1]) << 16);
            uint4* p = (uint4*)(Hs + (size_t)row * HF + q * 16);
            p[0] = make_uint4(u[0], u[1], u[2], u[3]);
            p[1] = make_uint4(u[4], u[5], u[6], u[7]);
        }
    }
}

// Aggregation (R13 version: full-row gathers): quarter-wave per node
// (16 lanes x 4 ch via uint2), 4 nodes/wave, depth-16 branch-free MLP batches.
// Stats: cross-quarter shfl_xor reduce -> per-wave LDS -> 128 striped atomics/block.
__global__ __launch_bounds__(256) void k_agg(const int* __restrict__ ro,
                                             const int* __restrict__ ss,
                                             const unsigned short* __restrict__ Hs,
                                             const float* __restrict__ rdeg,
                                             unsigned short* __restrict__ V16,
                                             float* __restrict__ partial, int n) {
    __shared__ float red[4][128];
    int t = threadIdx.x;
    int wid = blockIdx.x * 4 + (t >> 6);
    int lane = t & 63;
    int sub = lane >> 4;           // quarter id (node slot)
    int lq = lane & 15;            // lane within quarter
    int c4 = lq * 4;               // 4 channels per lane
    int node = wid * 4 + sub;
    bool vn = node < n;
    int safe = vn ? node : 0;
    int beg = 0, d = 0;
    if (vn) {
        beg = ro[node];
        d = ro[node + 1] - beg;
    }
    float4 acc = make_float4(0.f, 0.f, 0.f, 0.f);
    if (vn) {
        uint2 u = *(const uint2*)(Hs + ((size_t)node << 6) + c4);
        acc.x = bflo(u.x); acc.y = bfhi(u.x); acc.z = bflo(u.y); acc.w = bfhi(u.y);
    }
    int dm = d;
    dm = max(dm, __shfl_xor(dm, 16));
    dm = max(dm, __shfl_xor(dm, 32));
    for (int it = 0; it < dm; it += 16) {
        int myidx = (it + lq < d) ? ss[beg + it + lq] : -1;
        int sidx[16];
        float msk[16];
#pragma unroll
        for (int k = 0; k < 16; ++k) {
            int s = __shfl(myidx, (sub << 4) + k);
            sidx[k] = (s >= 0) ? s : safe;
            msk[k] = (s >= 0) ? 1.f : 0.f;
        }
        uint2 u[16];
#pragma unroll
        for (int k = 0; k < 16; ++k)
            u[k] = *(const uint2*)(Hs + ((size_t)sidx[k] << 6) + c4);
#pragma unroll
        for (int k = 0; k < 16; ++k) {
            acc.x = fmaf(msk[k], bflo(u[k].x), acc.x);
            acc.y = fmaf(msk[k], bfhi(u[k].x), acc.y);
            acc.z = fmaf(msk[k], bflo(u[k].y), acc.z);
            acc.w = fmaf(msk[k], bfhi(u[k].y), acc.w);
        }
    }
    float rv = vn ? rdeg[node] : 0.f;
    float v0 = acc.x * rv, v1 = acc.y * rv, v2 = acc.z * rv, v3 = acc.w * rv;
    if (vn) {
        unsigned int p0 = (unsigned int)f2bf(v0) | ((unsigned int)f2bf(v1) << 16);
        unsigned int p1 = (unsigned int)f2bf(v2) | ((unsigned int)f2bf(v3) << 16);
        *(uint2*)(V16 + ((size_t)node << 6) + c4) = make_uint2(p0, p1);
    }
    // fused BN stats: reduce across the 4 quarters (lanes with same lq)
    float s0 = v0, s1 = v1, s2 = v2, s3 = v3;
    float q0 = v0 * v0, q1 = v1 * v1, q2 = v2 * v2, q3 = v3 * v3;
#pragma unroll
    for (int m = 16; m <= 32; m <<= 1) {
        s0 += __shfl_xor(s0, m); s1 += __shfl_xor(s1, m);
        s2 += __shfl_xor(s2, m); s3 += __shfl_xor(s3, m);
        q0 += __shfl_xor(q0, m); q1 += __shfl_xor(q1, m);
        q2 += __shfl_xor(q2, m); q3 += __shfl_xor(q3, m);
    }
    if (sub == 0) {
        int w = t >> 6;
        red[w][c4 + 0] = s0; red[w][c4 + 1] = s1;
        red[w][c4 + 2] = s2; red[w][c4 + 3] = s3;
        red[w][64 + c4 + 0] = q0; red[w][64 + c4 + 1] = q1;
        red[w][64 + c4 + 2] = q2; red[w][64 + c4 + 3] = q3;
    }
    __syncthreads();
    if (t < 128) {
        float r = red[0][t] + red[1][t] + red[2][t] + red[3][t];
        atomicAdd(&partial[(blockIdx.x & (NPART - 1)) * 128 + t], r);
    }
}

// Pool: wave per 64 consecutive rows, run-flush atomics at graph boundaries.
// BN params from NPART-slot partials.
__global__ __launch_bounds__(256) void k_pool2(const unsigned short* __restrict__ V16,
                                               const float* __restrict__ SP,
                                               const float* __restrict__ g,
                                               const float* __restrict__ be,
                                               const int* __restrict__ batch,
                                               float* __restrict__ pool, int n) {
    __shared__ float sa_l[64], sb_l[64];
    int t = threadIdx.x;
    if (t < 64) {
        float s = 0.f, q = 0.f;
#pragma unroll
        for (int p = 0; p < NPART; ++p) {
            s += SP[p * 128 + t];
            q += SP[p * 128 + 64 + t];
        }
        float n_ = (float)NN;
        float mu = s / n_;
        float var = q / n_ - mu * mu;
        float a = g[t] * rsqrtf(var + 1e-5f);
        sa_l[t] = a;
        sb_l[t] = be[t] - mu * a;
    }
    __syncthreads();
    int wid = blockIdx.x * 4 + (t >> 6);
    int r0 = wid * 64;
    if (r0 >= n) return;
    int lane = t & 63;
    float sa = sa_l[lane], sb = sb_l[lane];
    int rend = min(r0 + 64, n);
    int cur = batch[r0];
    float s = 0.f;
    for (int r = r0; r < rend; ++r) {
        int b = batch[r];
        if (b != cur) {
            atomicAdd(&pool[(size_t)cur * HF + lane], s);
            s = 0.f;
            cur = b;
        }
        float v = bf2f(V16[(size_t)r * HF + lane]);
        s += fmaxf(fmaf(sa, v, sb), 0.f);
    }
    atomicAdd(&pool[(size_t)cur * HF + lane], s);
}

__global__ void k_cls(const float* __restrict__ pool, const float* __restrict__ Wc1,
                      const float* __restrict__ bc1, const float* __restrict__ Wc2,
                      const float* __restrict__ bc2, float* __restrict__ out) {
    __shared__ float pl[HF], hr[HF];
    int g = blockIdx.x, c = threadIdx.x;
    pl[c] = pool[g * HF + c];
    __syncthreads();
    float h = bc1[c];
#pragma unroll
    for (int k = 0; k < HF; ++k) h = fmaf(pl[k], Wc1[c * HF + k], h);
    hr[c] = fmaxf(h, 0.f);
    __syncthreads();
    if (c < OUTF) {
        float o = bc2[c];
#pragma unroll
        for (int k = 0; k < HF; ++k) o = fmaf(hr[k], Wc2[c * HF + k], o);
        out[g * OUTF + c] = o;
    }
}

extern "C" void kernel_launch(void* const* d_in, const int* in_sizes, int n_in,
                              void* d_out, int out_size, void* d_ws, size_t ws_size,
                              hipStream_t stream) {
    const float* x = (const float*)d_in[0];
    const int* edge = (const int*)d_in[1];
    const int* batch = (const int*)d_in[2];
    const float* W1 = (const float*)d_in[3];
    const float* b1 = (const float*)d_in[4];
    const float* g1 = (const float*)d_in[5];
    const float* be1 = (const float*)d_in[6];
    const float* W2 = (const float*)d_in[7];
    const float* b2 = (const float*)d_in[8];
    const float* g2 = (const float*)d_in[9];
    const float* be2 = (const float*)d_in[10];
    const float* W3 = (const float*)d_in[11];
    const float* b3 = (const float*)d_in[12];
    const float* g3 = (const float*)d_in[13];
    const float* be3 = (const float*)d_in[14];
    const float* Wc1 = (const float*)d_in[15];
    const float* bc1 = (const float*)d_in[16];
    const float* Wc2 = (const float*)d_in[17];
    const float* bc2 = (const float*)d_in[18];
    float* out = (float*)d_out;

    const int* src = edge;
    const int* dst = edge + NE;

    const size_t N64 = (size_t)NN * HF;
    const int NGC = NBUCK * NBLKP;                       // 200192
    unsigned short* V16 = (unsigned short*)d_ws;         // N*64 bf16
    unsigned short* Hs = V16 + N64;                      // N*64 bf16
    float* rdeg = (float*)(Hs + N64);                    // N
    float* part = rdeg + NN;                             // 3 * NPART*128 (per-layer partials)
    float* pool = part + 3 * NPART * 128;                // NG*64 (contiguous w/ part)
    int* gcount = (int*)(pool + (size_t)NG * HF);        // NGC
    int* goff = gcount + NGC;                            // NGC
    int* bsum = goff + NGC;                              // 256
    int* ro = bsum + 256;                                // N+1
    int* tmp = ro + NN + 1;                              // E
    int* ss = tmp + NE;                                  // E
    unsigned short* wp0 = (unsigned short*)(ss + NE);    // 8192 (W1 pack)
    unsigned short* wp1 = wp0 + 8192;                    // 4096 (W2 pack)
    unsigned short* wp2 = wp1 + 4096;                    // 4096 (W3 pack)

    // ---- front: bucket histogram + W pack + partial zero (one launch) ----
    k_front<<<NBLKP + 8 + (PARTF + 255) / 256, 256, 0, stream>>>(
        dst, gcount, W1, W2, W3, wp0, wp1, wp2, part);

    // ---- CSR build ----
    const int nblk = (NGC + 1023) / 1024;                // 196
    k_scan1<<<nblk, 256, 0, stream>>>(gcount, goff, bsum, NGC);
    k_scan2<<<1, 256, 0, stream>>>(bsum, nblk);
    kB_part<<<NBLKP, 256, 0, stream>>>(src, dst, goff, bsum, tmp);
    kC_build<<<NBUCK, 256, 0, stream>>>(goff, bsum, tmp, ss, ro, rdeg, NE);

    const unsigned short* gWp[3] = {wp0, wp1, wp2};
    const float* gb[3] = {b1, b2, b3};
    const float* gg[3] = {g1, g2, g3};
    const float* gbe[3] = {be1, be2, be3};

    const int tileblk = (NN + 63) / 64;
    const int aggblk = (NN + 15) / 16;        // 4 nodes/wave * 4 waves
    const int poolblk = ((NN + 63) / 64 + 3) / 4;

    for (int l = 0; l < 3; ++l) {
        if (l == 0)
            k_gemm_mfma<INF_, false><<<tileblk, 256, 0, stream>>>(x, (const unsigned short*)0,
                                                                  gWp[0], gb[0], rdeg, part,
                                                                  gg[0], gbe[0], Hs, NN);
        else
            k_gemm_mfma<HF, true><<<tileblk, 256, 0, stream>>>((const float*)0, V16,
                                                               gWp[l], gb[l], rdeg,
                                                               part + (l - 1) * NPART * 128,
                                                               gg[l - 1], gbe[l - 1], Hs, NN);
        k_agg<<<aggblk, 256, 0, stream>>>(ro, ss, Hs, rdeg, V16,
                                          part + l * NPART * 128, NN);
        if (l == 2)
            k_pool2<<<poolblk, 256, 0, stream>>>(V16, part + 2 * NPART * 128,
                                                 gg[2], gbe[2], batch, pool, NN);
    }

    k_cls<<<NG, HF, 0, stream>>>(pool, Wc1, bc1, Wc2, bc2, out);
}